// Round 3
// baseline (330.964 us; speedup 1.0000x reference)
//
#include <hip/hip_runtime.h>

typedef __attribute__((ext_vector_type(8))) short short8;
typedef __attribute__((ext_vector_type(4))) float f32x4;
typedef __attribute__((ext_vector_type(4))) unsigned short us4;
typedef unsigned short u16;

#define MFMA16(a, b, c) __builtin_amdgcn_mfma_f32_16x16x32_bf16(a, b, c, 0, 0, 0)

static __device__ __forceinline__ u16 f2bf(float f) {
  union { float f; unsigned u; } v; v.f = f;
  unsigned r = v.u + 0x7fffu + ((v.u >> 16) & 1u);
  return (u16)(r >> 16);
}

static __device__ __forceinline__ void gl_lds16(const u16* g, u16* l) {
  __builtin_amdgcn_global_load_lds((const __attribute__((address_space(1))) void*)g,
                                   (__attribute__((address_space(3))) void*)l,
                                   16, 0, 0);
}

// ---------------------------------------------------------------------------
// f32 -> bf16 convert, 8 elems/thread, grid-stride.
// ---------------------------------------------------------------------------
__global__ __launch_bounds__(256)
void cvt_bf16(const float* __restrict__ src, u16* __restrict__ dst, int n8)
{
  int i = blockIdx.x * 256 + threadIdx.x;
  const int stride = gridDim.x * 256;
  for (; i < n8; i += stride) {
    f32x4 a = ((const f32x4*)src)[2 * i];
    f32x4 b = ((const f32x4*)src)[2 * i + 1];
    short8 o;
    o[0] = (short)f2bf(a[0]); o[1] = (short)f2bf(a[1]);
    o[2] = (short)f2bf(a[2]); o[3] = (short)f2bf(a[3]);
    o[4] = (short)f2bf(b[0]); o[5] = (short)f2bf(b[1]);
    o[6] = (short)f2bf(b[2]); o[7] = (short)f2bf(b[3]);
    ((short8*)dst)[i] = o;
  }
}

// ---------------------------------------------------------------------------
// GEMM: C(M x N) = A(M x 1024) * B^T(N x 1024), bf16 in, f32 acc.
// MODE=1: A natural [m][1024]; epilogue scatters Q[bh][t][64] (x0.125),
//         K[bh][t][64], V transposed to VT[bh][dh][2048] into outp (=ws).
// MODE=2: A in headed layout [bh][t][64] (attention output aliased over Q);
//         f32 store to outf[m*1024+n].  (N = 1024)
// ---------------------------------------------------------------------------
template<int MODE>
__global__ __launch_bounds__(256)
void gemm_bt(const u16* __restrict__ A, const u16* __restrict__ B,
             u16* __restrict__ outp, float* __restrict__ outf)
{
  __shared__ u16 Ash[128 * 32];
  __shared__ u16 Bsh[128 * 32];
  const int tid = threadIdx.x;
  const int lane = tid & 63;
  const int l15 = lane & 15, g = lane >> 4;
  const int w = tid >> 6;
  const int wr = w >> 1, wc = w & 1;
  const long m0 = (long)blockIdx.x * 128;
  const long n0 = (long)blockIdx.y * 128;

  f32x4 acc[4][4] = {};

  // staging: 512 chunks of 16B per tile (A and B each), 2 chunks/thread
  const int c0 = tid, c1 = tid + 256;
  const long arow0 = m0 + (c0 >> 2), arow1 = m0 + (c1 >> 2);
  const u16* pa0;
  const u16* pa1;
  if (MODE == 2) {
    // headed A: element (m, k) at (b*16 + k/64)*131072 + t*64 + (k%64)
    int b0 = (int)(arow0 >> 11), t0 = (int)(arow0 & 2047);
    int b1 = (int)(arow1 >> 11), t1 = (int)(arow1 & 2047);
    pa0 = A + (size_t)(b0 * 16) * 131072u + (size_t)t0 * 64u + (c0 & 3) * 8;
    pa1 = A + (size_t)(b1 * 16) * 131072u + (size_t)t1 * 64u + (c1 & 3) * 8;
  } else {
    pa0 = A + arow0 * 1024 + (c0 & 3) * 8;
    pa1 = A + arow1 * 1024 + (c1 & 3) * 8;
  }
  const u16* pb0 = B + (n0 + (c0 >> 2)) * 1024 + (c0 & 3) * 8;
  const u16* pb1 = B + (n0 + (c1 >> 2)) * 1024 + (c1 & 3) * 8;
  u16* la0 = Ash + c0 * 8;
  u16* la1 = Ash + c1 * 8;
  u16* lb0 = Bsh + c0 * 8;
  u16* lb1 = Bsh + c1 * 8;

  // loop-invariant LDS fragment addresses
  const u16* afp[4];
  const u16* bfp[4];
  #pragma unroll
  for (int mi = 0; mi < 4; ++mi)
    afp[mi] = &Ash[(wr * 64 + mi * 16 + l15) * 32 + g * 8];
  #pragma unroll
  for (int ni = 0; ni < 4; ++ni)
    bfp[ni] = &Bsh[(wc * 64 + ni * 16 + l15) * 32 + g * 8];

  for (int k0 = 0; k0 < 1024; k0 += 32) {
    __syncthreads();
    gl_lds16(pa0, la0); gl_lds16(pa1, la1);
    gl_lds16(pb0, lb0); gl_lds16(pb1, lb1);
    if (MODE == 2) {
      long d = (k0 & 32) ? (131072 - 32) : 32;  // h-block crossing every 64
      pa0 += d; pa1 += d;
    } else {
      pa0 += 32; pa1 += 32;
    }
    pb0 += 32; pb1 += 32;
    __syncthreads();

    short8 af[4], bf[4];
    #pragma unroll
    for (int mi = 0; mi < 4; ++mi) af[mi] = *(const short8*)afp[mi];
    #pragma unroll
    for (int ni = 0; ni < 4; ++ni) bf[ni] = *(const short8*)bfp[ni];
    #pragma unroll
    for (int mi = 0; mi < 4; ++mi)
      #pragma unroll
      for (int ni = 0; ni < 4; ++ni)
        acc[mi][ni] = MFMA16(af[mi], bf[ni], acc[mi][ni]);
  }

  if (MODE == 2) {
    #pragma unroll
    for (int mi = 0; mi < 4; ++mi) {
      long m = m0 + wr * 64 + mi * 16 + g * 4;
      #pragma unroll
      for (int ni = 0; ni < 4; ++ni) {
        int n = (int)n0 + wc * 64 + ni * 16 + l15;
        #pragma unroll
        for (int r = 0; r < 4; ++r)
          outf[(m + r) * 1024 + n] = acc[mi][ni][r];
      }
    }
  } else {
    #pragma unroll
    for (int mi = 0; mi < 4; ++mi) {
      long m = m0 + wr * 64 + mi * 16 + g * 4;  // 4 consecutive rows m..m+3
      int b = (int)(m >> 11);
      int t = (int)(m & 2047);
      #pragma unroll
      for (int ni = 0; ni < 4; ++ni) {
        int e = (int)n0 + wc * 64 + ni * 16 + l15;   // 0..3071
        int sel = e >> 10;                            // 0=Q 1=K 2=V
        int ee = e & 1023;
        int h = ee >> 6, dh = ee & 63;
        size_t bh131k = (size_t)(b * 16 + h) * 131072u;
        if (sel < 2) {
          float sc = (sel == 0) ? 0.125f : 1.0f;     // fold 1/sqrt(64) into Q
          size_t base = (size_t)sel * 8388608u + bh131k + (size_t)t * 64u + dh;
          #pragma unroll
          for (int r = 0; r < 4; ++r)
            outp[base + (size_t)r * 64u] = f2bf(acc[mi][ni][r] * sc);
        } else {
          // V: write transposed, VT[bh][dh][t..t+3] (t % 4 == 0 -> 8B aligned)
          size_t base = 16777216u + bh131k + (size_t)dh * 2048u + (size_t)t;
          us4 v;
          #pragma unroll
          for (int r = 0; r < 4; ++r) v[r] = f2bf(acc[mi][ni][r]);
          *(us4*)&outp[base] = v;
        }
      }
    }
  }
}

// ---------------------------------------------------------------------------
// Causal flash attention. Q pre-scaled. Q/K: [bh][t][64], VT: [bh][dh][2048].
// Block: 256 thr (4 waves), 128 q-rows; wave w owns rows [q0+32w, q0+32w+32).
// KV tiles of 64. K/VT LDS tiles XOR-swizzled at 16B-unit granularity
// (rows are 128B -> unswizzled would be a 16-way bank conflict, G4).
// O is written over the Q region ([bh][t][64]): each block reads only its own
// Q rows (into regs, at start) and writes only those rows (at end) -> safe.
// ---------------------------------------------------------------------------
__global__ __launch_bounds__(256)
void attn(const u16* __restrict__ Q, const u16* __restrict__ K,
          const u16* __restrict__ VT, u16* __restrict__ O)
{
  __shared__ u16 Ksh[64 * 64];       // logical [kv][dh], swizzled
  __shared__ u16 Vsh[64 * 64];       // logical [dh][kv], swizzled
  __shared__ u16 Psh[4][32 * 64];    // per-wave [q][kv], swizzled

  const int tid = threadIdx.x;
  const int lane = tid & 63;
  const int l15 = lane & 15, g = lane >> 4;
  const int w = tid >> 6;
  const int bh = blockIdx.y;
  const int q0 = blockIdx.x * 128;
  const int qb = q0 + w * 32;

  const u16* Qp = Q + (size_t)bh * 131072u;
  const u16* Kp = K + (size_t)bh * 131072u;
  const u16* Vp = VT + (size_t)bh * 131072u;

  // Q fragments in registers (reused across all KV tiles)
  short8 qf[2][2];
  #pragma unroll
  for (int mi = 0; mi < 2; ++mi)
    #pragma unroll
    for (int kc = 0; kc < 2; ++kc)
      qf[mi][kc] = *(const short8*)&Qp[(qb + mi * 16 + l15) * 64 + kc * 32 + g * 8];

  f32x4 oacc[2][4] = {};
  float mrun[2][4], lrun[2][4];
  #pragma unroll
  for (int mi = 0; mi < 2; ++mi)
    #pragma unroll
    for (int r = 0; r < 4; ++r) { mrun[mi][r] = -1e30f; lrun[mi][r] = 0.f; }

  const int cA = tid, cB = tid + 256;
  const int rA = cA >> 3, uA = ((cA & 7) ^ (rA & 7)) * 8;
  const int rB = cB >> 3, uB = ((cB & 7) ^ (rB & 7)) * 8;

  for (int kv0 = 0; kv0 < q0 + 128; kv0 += 64) {
    __syncthreads();
    // K tile: source pre-swizzled so linear LDS == swizzled layout (rule #21)
    gl_lds16(Kp + (kv0 + rA) * 64 + uA, Ksh + cA * 8);
    gl_lds16(Kp + (kv0 + rB) * 64 + uB, Ksh + cB * 8);
    // VT tile: rows are dh, cols kv
    gl_lds16(Vp + (size_t)rA * 2048u + kv0 + uA, Vsh + cA * 8);
    gl_lds16(Vp + (size_t)rB * 2048u + kv0 + uB, Vsh + cB * 8);
    __syncthreads();

    if (kv0 > qb + 31) continue;   // fully masked for this wave (barriers done)

    // ---- S = Q K^T ----
    f32x4 s[2][4] = {};
    #pragma unroll
    for (int kc = 0; kc < 2; ++kc)
      #pragma unroll
      for (int ni = 0; ni < 4; ++ni) {
        int row = ni * 16 + l15;
        short8 kb = *(const short8*)&Ksh[row * 64 + (((kc * 4 + g) ^ (row & 7)) << 3)];
        #pragma unroll
        for (int mi = 0; mi < 2; ++mi)
          s[mi][ni] = MFMA16(qf[mi][kc], kb, s[mi][ni]);
      }

    // ---- causal mask (diagonal tiles only) ----
    if (kv0 + 63 > qb) {
      #pragma unroll
      for (int mi = 0; mi < 2; ++mi)
        #pragma unroll
        for (int ni = 0; ni < 4; ++ni)
          #pragma unroll
          for (int r = 0; r < 4; ++r)
            if (kv0 + ni * 16 + l15 > qb + mi * 16 + g * 4 + r)
              s[mi][ni][r] = -1e30f;
    }

    // ---- online softmax (16-lane shfl reduce per row) ----
    #pragma unroll
    for (int mi = 0; mi < 2; ++mi) {
      #pragma unroll
      for (int r = 0; r < 4; ++r) {
        float mx = fmaxf(fmaxf(s[mi][0][r], s[mi][1][r]),
                         fmaxf(s[mi][2][r], s[mi][3][r]));
        mx = fmaxf(mx, __shfl_xor(mx, 1));
        mx = fmaxf(mx, __shfl_xor(mx, 2));
        mx = fmaxf(mx, __shfl_xor(mx, 4));
        mx = fmaxf(mx, __shfl_xor(mx, 8));
        float mn = fmaxf(mrun[mi][r], mx);
        float sc = __expf(mrun[mi][r] - mn);
        mrun[mi][r] = mn;
        float rs = 0.f;
        #pragma unroll
        for (int ni = 0; ni < 4; ++ni) {
          float p = __expf(s[mi][ni][r] - mn);
          s[mi][ni][r] = p;
          rs += p;
        }
        rs += __shfl_xor(rs, 1);
        rs += __shfl_xor(rs, 2);
        rs += __shfl_xor(rs, 4);
        rs += __shfl_xor(rs, 8);
        lrun[mi][r] = lrun[mi][r] * sc + rs;
        #pragma unroll
        for (int nj = 0; nj < 4; ++nj) oacc[mi][nj][r] *= sc;
      }
    }

    // ---- P -> per-wave LDS (bf16, swizzled), re-fragment for PV ----
    u16* Pw = &Psh[w][0];
    #pragma unroll
    for (int mi = 0; mi < 2; ++mi)
      #pragma unroll
      for (int r = 0; r < 4; ++r) {
        int prow = mi * 16 + g * 4 + r;
        #pragma unroll
        for (int ni = 0; ni < 4; ++ni) {
          int col = ni * 16 + l15;
          Pw[prow * 64 + (((col >> 3) ^ (prow & 7)) << 3) + (col & 7)] =
              f2bf(s[mi][ni][r]);
        }
      }
    short8 pa[2][2];
    #pragma unroll
    for (int mi = 0; mi < 2; ++mi)
      #pragma unroll
      for (int kc = 0; kc < 2; ++kc) {
        int prow = mi * 16 + l15;
        pa[mi][kc] = *(const short8*)&Pw[prow * 64 + (((kc * 4 + g) ^ (prow & 7)) << 3)];
      }

    // ---- O += P V ----
    #pragma unroll
    for (int kc = 0; kc < 2; ++kc)
      #pragma unroll
      for (int nj = 0; nj < 4; ++nj) {
        int vrow = nj * 16 + l15;
        short8 vb = *(const short8*)&Vsh[vrow * 64 + (((kc * 4 + g) ^ (vrow & 7)) << 3)];
        #pragma unroll
        for (int mi = 0; mi < 2; ++mi)
          oacc[mi][nj] = MFMA16(pa[mi][kc], vb, oacc[mi][nj]);
      }
  }

  // ---- epilogue: O over Q region, [bh][t][64] ----
  #pragma unroll
  for (int mi = 0; mi < 2; ++mi)
    #pragma unroll
    for (int r = 0; r < 4; ++r) {
      float inv = 1.0f / lrun[mi][r];
      int t = qb + mi * 16 + g * 4 + r;
      size_t base = (size_t)bh * 131072u + (size_t)t * 64u;
      #pragma unroll
      for (int nj = 0; nj < 4; ++nj)
        O[base + nj * 16 + l15] = f2bf(oacc[mi][nj][r] * inv);
    }
}

// ---------------------------------------------------------------------------
extern "C" void kernel_launch(void* const* d_in, const int* in_sizes, int n_in,
                              void* d_out, int out_size, void* d_ws, size_t ws_size,
                              hipStream_t stream)
{
  (void)in_sizes; (void)n_in; (void)out_size; (void)ws_size;
  const float* x    = (const float*)d_in[0];   // [8192][1024] f32
  const float* wqkv = (const float*)d_in[1];   // [3072][1024] f32
  const float* wout = (const float*)d_in[2];   // [1024][1024] f32
  u16* ws  = (u16*)d_ws;
  u16* Qw   = ws;                  // Q [bh][t][64]; later attn O (same layout)
  u16* Kw   = ws + 8388608;        // K [bh][t][64]
  u16* VTw  = ws + 16777216;       // VT [bh][dh][2048]
  u16* wqb  = ws + 25165824;       // w_qkv bf16 [3072][1024]
  u16* wob  = ws + 28311552;       // w_out bf16 [1024][1024]
  u16* xb   = (u16*)d_out;         // x bf16 [8192][1024] staged in d_out
  float* y  = (float*)d_out;       // final f32 output (overwrites xb)

  hipLaunchKernelGGL(cvt_bf16, dim3(2048), dim3(256), 0, stream, x,    xb,  1048576);
  hipLaunchKernelGGL(cvt_bf16, dim3(1536), dim3(256), 0, stream, wqkv, wqb, 393216);
  hipLaunchKernelGGL(cvt_bf16, dim3(512),  dim3(256), 0, stream, wout, wob, 131072);
  hipLaunchKernelGGL((gemm_bt<1>), dim3(64, 24), dim3(256), 0, stream, xb, wqb, ws, (float*)nullptr);
  hipLaunchKernelGGL(attn,         dim3(16, 64), dim3(256), 0, stream, Qw, Kw, VTw, Qw);
  hipLaunchKernelGGL((gemm_bt<2>), dim3(64, 8),  dim3(256), 0, stream, Qw, wob, (u16*)nullptr, y);
}

// Round 4
// 232.925 us; speedup vs baseline: 1.4209x; 1.4209x over previous
//
#include <hip/hip_runtime.h>

typedef __attribute__((ext_vector_type(8))) short short8;
typedef __attribute__((ext_vector_type(4))) float f32x4;
typedef __attribute__((ext_vector_type(4))) unsigned short us4;
typedef unsigned short u16;

#define MFMA16(a, b, c) __builtin_amdgcn_mfma_f32_16x16x32_bf16(a, b, c, 0, 0, 0)

static __device__ __forceinline__ u16 f2bf(float f) {
  union { float f; unsigned u; } v; v.f = f;
  unsigned r = v.u + 0x7fffu + ((v.u >> 16) & 1u);
  return (u16)(r >> 16);
}

static __device__ __forceinline__ void gl_lds16(const u16* g, u16* l) {
  __builtin_amdgcn_global_load_lds((const __attribute__((address_space(1))) void*)g,
                                   (__attribute__((address_space(3))) void*)l,
                                   16, 0, 0);
}

// ---------------------------------------------------------------------------
// f32 -> bf16 convert, 8 elems/thread, grid-stride.
// ---------------------------------------------------------------------------
__global__ __launch_bounds__(256)
void cvt_bf16(const float* __restrict__ src, u16* __restrict__ dst, int n8)
{
  int i = blockIdx.x * 256 + threadIdx.x;
  const int stride = gridDim.x * 256;
  for (; i < n8; i += stride) {
    f32x4 a = ((const f32x4*)src)[2 * i];
    f32x4 b = ((const f32x4*)src)[2 * i + 1];
    short8 o;
    o[0] = (short)f2bf(a[0]); o[1] = (short)f2bf(a[1]);
    o[2] = (short)f2bf(a[2]); o[3] = (short)f2bf(a[3]);
    o[4] = (short)f2bf(b[0]); o[5] = (short)f2bf(b[1]);
    o[6] = (short)f2bf(b[2]); o[7] = (short)f2bf(b[3]);
    ((short8*)dst)[i] = o;
  }
}

// ---------------------------------------------------------------------------
// GEMM: C(M x N) = A(M x 1024) * B^T(N x 1024), bf16 in, f32 acc.
// MODE=1: A natural [m][1024]; epilogue scatters Q[bh][t][64] (x0.125),
//         K[bh][t][64], V transposed to VT[bh][dh][2048] into outp (=ws).
// MODE=2: A in headed layout [bh][t][64] (attention output aliased over Q);
//         f32 store to outf[m*1024+n].  (N = 1024)
// ---------------------------------------------------------------------------
template<int MODE>
__global__ __launch_bounds__(256)
void gemm_bt(const u16* __restrict__ A, const u16* __restrict__ B,
             u16* __restrict__ outp, float* __restrict__ outf)
{
  __shared__ u16 Ash[128 * 32];
  __shared__ u16 Bsh[128 * 32];
  const int tid = threadIdx.x;
  const int lane = tid & 63;
  const int l15 = lane & 15, g = lane >> 4;
  const int w = tid >> 6;
  const int wr = w >> 1, wc = w & 1;
  const long m0 = (long)blockIdx.x * 128;
  const long n0 = (long)blockIdx.y * 128;

  f32x4 acc[4][4] = {};

  // staging: 512 chunks of 16B per tile (A and B each), 2 chunks/thread
  const int c0 = tid, c1 = tid + 256;
  const long arow0 = m0 + (c0 >> 2), arow1 = m0 + (c1 >> 2);
  const u16* pa0;
  const u16* pa1;
  if (MODE == 2) {
    // headed A: element (m, k) at (b*16 + k/64)*131072 + t*64 + (k%64)
    int b0 = (int)(arow0 >> 11), t0 = (int)(arow0 & 2047);
    int b1 = (int)(arow1 >> 11), t1 = (int)(arow1 & 2047);
    pa0 = A + (size_t)(b0 * 16) * 131072u + (size_t)t0 * 64u + (c0 & 3) * 8;
    pa1 = A + (size_t)(b1 * 16) * 131072u + (size_t)t1 * 64u + (c1 & 3) * 8;
  } else {
    pa0 = A + arow0 * 1024 + (c0 & 3) * 8;
    pa1 = A + arow1 * 1024 + (c1 & 3) * 8;
  }
  const u16* pb0 = B + (n0 + (c0 >> 2)) * 1024 + (c0 & 3) * 8;
  const u16* pb1 = B + (n0 + (c1 >> 2)) * 1024 + (c1 & 3) * 8;
  u16* la0 = Ash + c0 * 8;
  u16* la1 = Ash + c1 * 8;
  u16* lb0 = Bsh + c0 * 8;
  u16* lb1 = Bsh + c1 * 8;

  // loop-invariant LDS fragment addresses
  const u16* afp[4];
  const u16* bfp[4];
  #pragma unroll
  for (int mi = 0; mi < 4; ++mi)
    afp[mi] = &Ash[(wr * 64 + mi * 16 + l15) * 32 + g * 8];
  #pragma unroll
  for (int ni = 0; ni < 4; ++ni)
    bfp[ni] = &Bsh[(wc * 64 + ni * 16 + l15) * 32 + g * 8];

  for (int k0 = 0; k0 < 1024; k0 += 32) {
    __syncthreads();
    gl_lds16(pa0, la0); gl_lds16(pa1, la1);
    gl_lds16(pb0, lb0); gl_lds16(pb1, lb1);
    if (MODE == 2) {
      long d = (k0 & 32) ? (131072 - 32) : 32;  // h-block crossing every 64
      pa0 += d; pa1 += d;
    } else {
      pa0 += 32; pa1 += 32;
    }
    pb0 += 32; pb1 += 32;
    __syncthreads();

    short8 af[4], bf[4];
    #pragma unroll
    for (int mi = 0; mi < 4; ++mi) af[mi] = *(const short8*)afp[mi];
    #pragma unroll
    for (int ni = 0; ni < 4; ++ni) bf[ni] = *(const short8*)bfp[ni];
    #pragma unroll
    for (int mi = 0; mi < 4; ++mi)
      #pragma unroll
      for (int ni = 0; ni < 4; ++ni)
        acc[mi][ni] = MFMA16(af[mi], bf[ni], acc[mi][ni]);
  }

  if (MODE == 2) {
    #pragma unroll
    for (int mi = 0; mi < 4; ++mi) {
      long m = m0 + wr * 64 + mi * 16 + g * 4;
      #pragma unroll
      for (int ni = 0; ni < 4; ++ni) {
        int n = (int)n0 + wc * 64 + ni * 16 + l15;
        #pragma unroll
        for (int r = 0; r < 4; ++r)
          outf[(m + r) * 1024 + n] = acc[mi][ni][r];
      }
    }
  } else {
    #pragma unroll
    for (int mi = 0; mi < 4; ++mi) {
      long m = m0 + wr * 64 + mi * 16 + g * 4;  // 4 consecutive rows m..m+3
      int b = (int)(m >> 11);
      int t = (int)(m & 2047);
      #pragma unroll
      for (int ni = 0; ni < 4; ++ni) {
        int e = (int)n0 + wc * 64 + ni * 16 + l15;   // 0..3071
        int sel = e >> 10;                            // 0=Q 1=K 2=V
        int ee = e & 1023;
        int h = ee >> 6, dh = ee & 63;
        size_t bh131k = (size_t)(b * 16 + h) * 131072u;
        if (sel < 2) {
          float sc = (sel == 0) ? 0.125f : 1.0f;     // fold 1/sqrt(64) into Q
          size_t base = (size_t)sel * 8388608u + bh131k + (size_t)t * 64u + dh;
          #pragma unroll
          for (int r = 0; r < 4; ++r)
            outp[base + (size_t)r * 64u] = f2bf(acc[mi][ni][r] * sc);
        } else {
          // V: write transposed, VT[bh][dh][t..t+3] (t % 4 == 0 -> 8B aligned)
          size_t base = 16777216u + bh131k + (size_t)dh * 2048u + (size_t)t;
          us4 v;
          #pragma unroll
          for (int r = 0; r < 4; ++r) v[r] = f2bf(acc[mi][ni][r]);
          *(us4*)&outp[base] = v;
        }
      }
    }
  }
}

// ---------------------------------------------------------------------------
// Causal flash attention. Q pre-scaled. Q/K: [bh][t][64], VT: [bh][dh][2048].
// 1D grid, heavy-first: qi = 15 - bid/64 (heaviest q-blocks dispatch first,
// fixes the causal-triangle tail that showed as 11% occupancy).
// Double-buffered K/V staging with counted vmcnt + raw s_barrier (T3/T4
// minimum 2-phase): loads for tile t+1 stay in flight across tile t's
// compute; never vmcnt(0) mid-loop (avoids __syncthreads' vmcnt(0) drain).
// K/VT LDS tiles XOR-swizzled at 16B granularity (128B rows, G4).
// O is written over the Q region ([bh][t][64]): each block reads only its own
// Q rows (into regs, at start) and writes only those rows (at end) -> safe.
// ---------------------------------------------------------------------------
__global__ __launch_bounds__(256)
void attn(const u16* __restrict__ Q, const u16* __restrict__ K,
          const u16* __restrict__ VT, u16* __restrict__ O)
{
  __shared__ u16 Ksh[2][64 * 64];    // logical [kv][dh], swizzled, dbuf
  __shared__ u16 Vsh[2][64 * 64];    // logical [dh][kv], swizzled, dbuf
  __shared__ u16 Psh[4][32 * 64];    // per-wave [q][kv], swizzled

  const int tid = threadIdx.x;
  const int lane = tid & 63;
  const int l15 = lane & 15, g = lane >> 4;
  const int w = tid >> 6;
  const int bid = blockIdx.x;
  const int qi = 15 - (bid >> 6);    // heavy-first
  const int bh = bid & 63;
  const int q0 = qi * 128;
  const int qb = q0 + w * 32;
  const int nt = qi * 2 + 2;         // KV tiles for this block

  const u16* Qp = Q + (size_t)bh * 131072u;
  const u16* Kp = K + (size_t)bh * 131072u;
  const u16* Vp = VT + (size_t)bh * 131072u;

  // Q fragments in registers (reused across all KV tiles)
  short8 qf[2][2];
  #pragma unroll
  for (int mi = 0; mi < 2; ++mi)
    #pragma unroll
    for (int kc = 0; kc < 2; ++kc)
      qf[mi][kc] = *(const short8*)&Qp[(qb + mi * 16 + l15) * 64 + kc * 32 + g * 8];

  f32x4 oacc[2][4] = {};
  float mrun[2][4], lrun[2][4];
  #pragma unroll
  for (int mi = 0; mi < 2; ++mi)
    #pragma unroll
    for (int r = 0; r < 4; ++r) { mrun[mi][r] = -1e30f; lrun[mi][r] = 0.f; }

  const int cA = tid, cB = tid + 256;
  const int rA = cA >> 3, uA = ((cA & 7) ^ (rA & 7)) * 8;
  const int rB = cB >> 3, uB = ((cB & 7) ^ (rB & 7)) * 8;

  // source pre-swizzled so linear LDS dest == swizzled layout (rule #21)
#define STAGE(kv0s, b) do {                                            \
    gl_lds16(Kp + ((kv0s) + rA) * 64 + uA, Ksh[b] + cA * 8);           \
    gl_lds16(Kp + ((kv0s) + rB) * 64 + uB, Ksh[b] + cB * 8);           \
    gl_lds16(Vp + (size_t)rA * 2048u + (kv0s) + uA, Vsh[b] + cA * 8);  \
    gl_lds16(Vp + (size_t)rB * 2048u + (kv0s) + uB, Vsh[b] + cB * 8);  \
  } while (0)

  STAGE(0, 0);
  int cur = 0;

  for (int ti = 0; ti < nt; ++ti) {
    const int kv0 = ti * 64;
    if (ti + 1 < nt) {
      STAGE(kv0 + 64, cur ^ 1);
      asm volatile("s_waitcnt vmcnt(4)" ::: "memory");  // cur's 4 loads done
    } else {
      asm volatile("s_waitcnt vmcnt(0)" ::: "memory");
    }
    __builtin_amdgcn_s_barrier();
    __builtin_amdgcn_sched_barrier(0);

    if (kv0 <= qb + 31) {            // not fully masked for this wave
      const u16* Kb = Ksh[cur];
      const u16* Vb = Vsh[cur];

      // ---- S = Q K^T ----
      f32x4 s[2][4] = {};
      #pragma unroll
      for (int kc = 0; kc < 2; ++kc)
        #pragma unroll
        for (int ni = 0; ni < 4; ++ni) {
          int row = ni * 16 + l15;
          short8 kb = *(const short8*)&Kb[row * 64 + (((kc * 4 + g) ^ (row & 7)) << 3)];
          #pragma unroll
          for (int mi = 0; mi < 2; ++mi)
            s[mi][ni] = MFMA16(qf[mi][kc], kb, s[mi][ni]);
        }

      // ---- causal mask (diagonal tiles only) ----
      if (kv0 + 63 > qb) {
        #pragma unroll
        for (int mi = 0; mi < 2; ++mi)
          #pragma unroll
          for (int ni = 0; ni < 4; ++ni)
            #pragma unroll
            for (int r = 0; r < 4; ++r)
              if (kv0 + ni * 16 + l15 > qb + mi * 16 + g * 4 + r)
                s[mi][ni][r] = -1e30f;
      }

      // ---- online softmax (16-lane shfl reduce per row) ----
      #pragma unroll
      for (int mi = 0; mi < 2; ++mi) {
        #pragma unroll
        for (int r = 0; r < 4; ++r) {
          float mx = fmaxf(fmaxf(s[mi][0][r], s[mi][1][r]),
                           fmaxf(s[mi][2][r], s[mi][3][r]));
          mx = fmaxf(mx, __shfl_xor(mx, 1));
          mx = fmaxf(mx, __shfl_xor(mx, 2));
          mx = fmaxf(mx, __shfl_xor(mx, 4));
          mx = fmaxf(mx, __shfl_xor(mx, 8));
          float mn = fmaxf(mrun[mi][r], mx);
          float sc = __expf(mrun[mi][r] - mn);
          mrun[mi][r] = mn;
          float rs = 0.f;
          #pragma unroll
          for (int ni = 0; ni < 4; ++ni) {
            float p = __expf(s[mi][ni][r] - mn);
            s[mi][ni][r] = p;
            rs += p;
          }
          rs += __shfl_xor(rs, 1);
          rs += __shfl_xor(rs, 2);
          rs += __shfl_xor(rs, 4);
          rs += __shfl_xor(rs, 8);
          lrun[mi][r] = lrun[mi][r] * sc + rs;
          #pragma unroll
          for (int nj = 0; nj < 4; ++nj) oacc[mi][nj][r] *= sc;
        }
      }

      // ---- P -> per-wave LDS (bf16, swizzled), re-fragment for PV ----
      u16* Pw = &Psh[w][0];
      #pragma unroll
      for (int mi = 0; mi < 2; ++mi)
        #pragma unroll
        for (int r = 0; r < 4; ++r) {
          int prow = mi * 16 + g * 4 + r;
          #pragma unroll
          for (int ni = 0; ni < 4; ++ni) {
            int col = ni * 16 + l15;
            Pw[prow * 64 + (((col >> 3) ^ (prow & 7)) << 3) + (col & 7)] =
                f2bf(s[mi][ni][r]);
          }
        }
      short8 pa[2][2];
      #pragma unroll
      for (int mi = 0; mi < 2; ++mi)
        #pragma unroll
        for (int kc = 0; kc < 2; ++kc) {
          int prow = mi * 16 + l15;
          pa[mi][kc] = *(const short8*)&Pw[prow * 64 + (((kc * 4 + g) ^ (prow & 7)) << 3)];
        }

      // ---- O += P V ----
      #pragma unroll
      for (int kc = 0; kc < 2; ++kc)
        #pragma unroll
        for (int nj = 0; nj < 4; ++nj) {
          int vrow = nj * 16 + l15;
          short8 vb = *(const short8*)&Vb[vrow * 64 + (((kc * 4 + g) ^ (vrow & 7)) << 3)];
          #pragma unroll
          for (int mi = 0; mi < 2; ++mi)
            oacc[mi][nj] = MFMA16(pa[mi][kc], vb, oacc[mi][nj]);
        }
    }

    __builtin_amdgcn_sched_barrier(0);
    __builtin_amdgcn_s_barrier();    // all reads of buf[cur] done -> reusable
    cur ^= 1;
  }
#undef STAGE

  // ---- epilogue: O over Q region, [bh][t][64] ----
  #pragma unroll
  for (int mi = 0; mi < 2; ++mi)
    #pragma unroll
    for (int r = 0; r < 4; ++r) {
      float inv = 1.0f / lrun[mi][r];
      int t = qb + mi * 16 + g * 4 + r;
      size_t base = (size_t)bh * 131072u + (size_t)t * 64u;
      #pragma unroll
      for (int nj = 0; nj < 4; ++nj)
        O[base + nj * 16 + l15] = f2bf(oacc[mi][nj][r] * inv);
    }
}

// ---------------------------------------------------------------------------
extern "C" void kernel_launch(void* const* d_in, const int* in_sizes, int n_in,
                              void* d_out, int out_size, void* d_ws, size_t ws_size,
                              hipStream_t stream)
{
  (void)in_sizes; (void)n_in; (void)out_size; (void)ws_size;
  const float* x    = (const float*)d_in[0];   // [8192][1024] f32
  const float* wqkv = (const float*)d_in[1];   // [3072][1024] f32
  const float* wout = (const float*)d_in[2];   // [1024][1024] f32
  u16* ws  = (u16*)d_ws;
  u16* Qw   = ws;                  // Q [bh][t][64]; later attn O (same layout)
  u16* Kw   = ws + 8388608;        // K [bh][t][64]
  u16* VTw  = ws + 16777216;       // VT [bh][dh][2048]
  u16* wqb  = ws + 25165824;       // w_qkv bf16 [3072][1024]
  u16* wob  = ws + 28311552;       // w_out bf16 [1024][1024]
  u16* xb   = (u16*)d_out;         // x bf16 [8192][1024] staged in d_out
  float* y  = (float*)d_out;       // final f32 output (overwrites xb)

  hipLaunchKernelGGL(cvt_bf16, dim3(2048), dim3(256), 0, stream, x,    xb,  1048576);
  hipLaunchKernelGGL(cvt_bf16, dim3(1536), dim3(256), 0, stream, wqkv, wqb, 393216);
  hipLaunchKernelGGL(cvt_bf16, dim3(512),  dim3(256), 0, stream, wout, wob, 131072);
  hipLaunchKernelGGL((gemm_bt<1>), dim3(64, 24), dim3(256), 0, stream, xb, wqb, ws, (float*)nullptr);
  hipLaunchKernelGGL(attn,         dim3(1024),   dim3(256), 0, stream, Qw, Kw, VTw, Qw);
  hipLaunchKernelGGL((gemm_bt<2>), dim3(64, 8),  dim3(256), 0, stream, Qw, wob, (u16*)nullptr, y);
}

// Round 5
// 198.709 us; speedup vs baseline: 1.6656x; 1.1722x over previous
//
#include <hip/hip_runtime.h>

typedef __attribute__((ext_vector_type(8))) short short8;
typedef __attribute__((ext_vector_type(4))) float f32x4;
typedef __attribute__((ext_vector_type(4))) unsigned short us4;
typedef unsigned short u16;

#define MFMA16(a, b, c) __builtin_amdgcn_mfma_f32_16x16x32_bf16(a, b, c, 0, 0, 0)

static __device__ __forceinline__ u16 f2bf(float f) {
  union { float f; unsigned u; } v; v.f = f;
  unsigned r = v.u + 0x7fffu + ((v.u >> 16) & 1u);
  return (u16)(r >> 16);
}

static __device__ __forceinline__ unsigned cvtpk(float lo, float hi) {
  unsigned r;
  asm("v_cvt_pk_bf16_f32 %0, %1, %2" : "=v"(r) : "v"(lo), "v"(hi));
  return r;
}

static __device__ __forceinline__ void gl_lds16(const u16* g, u16* l) {
  __builtin_amdgcn_global_load_lds((const __attribute__((address_space(1))) void*)g,
                                   (__attribute__((address_space(3))) void*)l,
                                   16, 0, 0);
}

// ---------------------------------------------------------------------------
// f32 -> bf16 convert, 8 elems/thread, grid-stride.
// ---------------------------------------------------------------------------
__global__ __launch_bounds__(256)
void cvt_bf16(const float* __restrict__ src, u16* __restrict__ dst, int n8)
{
  int i = blockIdx.x * 256 + threadIdx.x;
  const int stride = gridDim.x * 256;
  for (; i < n8; i += stride) {
    f32x4 a = ((const f32x4*)src)[2 * i];
    f32x4 b = ((const f32x4*)src)[2 * i + 1];
    short8 o;
    o[0] = (short)f2bf(a[0]); o[1] = (short)f2bf(a[1]);
    o[2] = (short)f2bf(a[2]); o[3] = (short)f2bf(a[3]);
    o[4] = (short)f2bf(b[0]); o[5] = (short)f2bf(b[1]);
    o[6] = (short)f2bf(b[2]); o[7] = (short)f2bf(b[3]);
    ((short8*)dst)[i] = o;
  }
}

// ---------------------------------------------------------------------------
// GEMM: C(M x N) = A(M x 1024) * B^T(N x 1024), bf16 in, f32 acc.
// MODE=1: A natural [m][1024]; epilogue scatters Q[bh][t][64] (x0.125),
//         K[bh][t][64], V transposed to VT[bh][dh][2048] into outp (=ws).
// MODE=2: A in headed layout [bh][t][64] (attention output aliased over Q);
//         f32 store to outf[m*1024+n].  (N = 1024)
// ---------------------------------------------------------------------------
template<int MODE>
__global__ __launch_bounds__(256)
void gemm_bt(const u16* __restrict__ A, const u16* __restrict__ B,
             u16* __restrict__ outp, float* __restrict__ outf)
{
  __shared__ u16 Ash[128 * 32];
  __shared__ u16 Bsh[128 * 32];
  const int tid = threadIdx.x;
  const int lane = tid & 63;
  const int l15 = lane & 15, g = lane >> 4;
  const int w = tid >> 6;
  const int wr = w >> 1, wc = w & 1;
  const long m0 = (long)blockIdx.x * 128;
  const long n0 = (long)blockIdx.y * 128;

  f32x4 acc[4][4] = {};

  // staging: 512 chunks of 16B per tile (A and B each), 2 chunks/thread
  const int c0 = tid, c1 = tid + 256;
  const long arow0 = m0 + (c0 >> 2), arow1 = m0 + (c1 >> 2);
  const u16* pa0;
  const u16* pa1;
  if (MODE == 2) {
    // headed A: element (m, k) at (b*16 + k/64)*131072 + t*64 + (k%64)
    int b0 = (int)(arow0 >> 11), t0 = (int)(arow0 & 2047);
    int b1 = (int)(arow1 >> 11), t1 = (int)(arow1 & 2047);
    pa0 = A + (size_t)(b0 * 16) * 131072u + (size_t)t0 * 64u + (c0 & 3) * 8;
    pa1 = A + (size_t)(b1 * 16) * 131072u + (size_t)t1 * 64u + (c1 & 3) * 8;
  } else {
    pa0 = A + arow0 * 1024 + (c0 & 3) * 8;
    pa1 = A + arow1 * 1024 + (c1 & 3) * 8;
  }
  const u16* pb0 = B + (n0 + (c0 >> 2)) * 1024 + (c0 & 3) * 8;
  const u16* pb1 = B + (n0 + (c1 >> 2)) * 1024 + (c1 & 3) * 8;
  u16* la0 = Ash + c0 * 8;
  u16* la1 = Ash + c1 * 8;
  u16* lb0 = Bsh + c0 * 8;
  u16* lb1 = Bsh + c1 * 8;

  // loop-invariant LDS fragment addresses
  const u16* afp[4];
  const u16* bfp[4];
  #pragma unroll
  for (int mi = 0; mi < 4; ++mi)
    afp[mi] = &Ash[(wr * 64 + mi * 16 + l15) * 32 + g * 8];
  #pragma unroll
  for (int ni = 0; ni < 4; ++ni)
    bfp[ni] = &Bsh[(wc * 64 + ni * 16 + l15) * 32 + g * 8];

  for (int k0 = 0; k0 < 1024; k0 += 32) {
    __syncthreads();
    gl_lds16(pa0, la0); gl_lds16(pa1, la1);
    gl_lds16(pb0, lb0); gl_lds16(pb1, lb1);
    if (MODE == 2) {
      long d = (k0 & 32) ? (131072 - 32) : 32;  // h-block crossing every 64
      pa0 += d; pa1 += d;
    } else {
      pa0 += 32; pa1 += 32;
    }
    pb0 += 32; pb1 += 32;
    __syncthreads();

    short8 af[4], bf[4];
    #pragma unroll
    for (int mi = 0; mi < 4; ++mi) af[mi] = *(const short8*)afp[mi];
    #pragma unroll
    for (int ni = 0; ni < 4; ++ni) bf[ni] = *(const short8*)bfp[ni];
    #pragma unroll
    for (int mi = 0; mi < 4; ++mi)
      #pragma unroll
      for (int ni = 0; ni < 4; ++ni)
        acc[mi][ni] = MFMA16(af[mi], bf[ni], acc[mi][ni]);
  }

  if (MODE == 2) {
    #pragma unroll
    for (int mi = 0; mi < 4; ++mi) {
      long m = m0 + wr * 64 + mi * 16 + g * 4;
      #pragma unroll
      for (int ni = 0; ni < 4; ++ni) {
        int n = (int)n0 + wc * 64 + ni * 16 + l15;
        #pragma unroll
        for (int r = 0; r < 4; ++r)
          outf[(m + r) * 1024 + n] = acc[mi][ni][r];
      }
    }
  } else {
    #pragma unroll
    for (int mi = 0; mi < 4; ++mi) {
      long m = m0 + wr * 64 + mi * 16 + g * 4;  // 4 consecutive rows m..m+3
      int b = (int)(m >> 11);
      int t = (int)(m & 2047);
      #pragma unroll
      for (int ni = 0; ni < 4; ++ni) {
        int e = (int)n0 + wc * 64 + ni * 16 + l15;   // 0..3071
        int sel = e >> 10;                            // 0=Q 1=K 2=V
        int ee = e & 1023;
        int h = ee >> 6, dh = ee & 63;
        size_t bh131k = (size_t)(b * 16 + h) * 131072u;
        if (sel < 2) {
          float sc = (sel == 0) ? 0.125f : 1.0f;     // fold 1/sqrt(64) into Q
          size_t base = (size_t)sel * 8388608u + bh131k + (size_t)t * 64u + dh;
          #pragma unroll
          for (int r = 0; r < 4; ++r)
            outp[base + (size_t)r * 64u] = f2bf(acc[mi][ni][r] * sc);
        } else {
          // V: write transposed, VT[bh][dh][t..t+3] (t % 4 == 0 -> 8B aligned)
          size_t base = 16777216u + bh131k + (size_t)dh * 2048u + (size_t)t;
          us4 v;
          #pragma unroll
          for (int r = 0; r < 4; ++r) v[r] = f2bf(acc[mi][ni][r]);
          *(us4*)&outp[base] = v;
        }
      }
    }
  }
}

// ---------------------------------------------------------------------------
// Causal flash attention, swapped-QK^T form. Q pre-scaled.
// Q/K: [bh][t][64], VT: [bh][dh][2048].
// S^T = mfma(K,Q): lane owns q = mi*16+l15, k = ni*16+g*4+r  -> row-softmax is
// 15 in-lane fmax + 2 shfls; P packs to bf16 via v_cvt_pk (4 k-consecutive per
// reg) -> ds_write_b64; PV = mfma(V^T,P) accumulates O^T (q=l15, d=g*4+r) so
// the rescale scalar is lane-uniform and the epilogue stores packed 8B.
// Heavy-first 1D grid + double-buffered staging with counted vmcnt (T3/T4).
// LDS 40KB -> 4 blocks/CU; grid fully resident.
// O is written over the Q region ([bh][t][64]): each block reads only its own
// Q rows (into regs, at start) and writes only those rows (at end) -> safe.
// ---------------------------------------------------------------------------
__global__ __launch_bounds__(256, 4)
void attn(const u16* __restrict__ Q, const u16* __restrict__ K,
          const u16* __restrict__ VT, u16* __restrict__ O)
{
  __shared__ u16 Ksh[2][64 * 64];    // logical [kv][dh], swizzled, dbuf
  __shared__ u16 Vsh[2][64 * 64];    // logical [dh][kv], swizzled, dbuf
  __shared__ u16 Psh[4][16 * 64];    // per-wave [q%16][kv], swizzled, mi-reused

  const int tid = threadIdx.x;
  const int lane = tid & 63;
  const int l15 = lane & 15, g = lane >> 4;
  const int w = tid >> 6;
  const int bid = blockIdx.x;
  const int qi = 15 - (bid >> 6);    // heavy-first
  const int bh = bid & 63;
  const int q0 = qi * 128;
  const int qb = q0 + w * 32;
  const int nt = qi * 2 + 2;         // KV tiles for this block

  const u16* Qp = Q + (size_t)bh * 131072u;
  const u16* Kp = K + (size_t)bh * 131072u;
  const u16* Vp = VT + (size_t)bh * 131072u;

  // Q fragments in registers (B-frag: lane l15 = q row, g*8.. = d)
  short8 qf[2][2];
  #pragma unroll
  for (int mi = 0; mi < 2; ++mi)
    #pragma unroll
    for (int kc = 0; kc < 2; ++kc)
      qf[mi][kc] = *(const short8*)&Qp[(qb + mi * 16 + l15) * 64 + kc * 32 + g * 8];

  f32x4 oacc[2][4] = {};             // O^T: q = mi*16+l15, d = nj*16+g*4+r
  float mrun[2] = {-1e30f, -1e30f};
  float lrun[2] = {0.f, 0.f};

  const int cA = tid, cB = tid + 256;
  const int rA = cA >> 3, uA = ((cA & 7) ^ (rA & 7)) * 8;
  const int rB = cB >> 3, uB = ((cB & 7) ^ (rB & 7)) * 8;

  // source pre-swizzled so linear LDS dest == swizzled layout (rule #21)
#define STAGE(kv0s, b) do {                                            \
    gl_lds16(Kp + ((kv0s) + rA) * 64 + uA, Ksh[b] + cA * 8);           \
    gl_lds16(Kp + ((kv0s) + rB) * 64 + uB, Ksh[b] + cB * 8);           \
    gl_lds16(Vp + (size_t)rA * 2048u + (kv0s) + uA, Vsh[b] + cA * 8);  \
    gl_lds16(Vp + (size_t)rB * 2048u + (kv0s) + uB, Vsh[b] + cB * 8);  \
  } while (0)

  STAGE(0, 0);
  int cur = 0;

  for (int ti = 0; ti < nt; ++ti) {
    const int kv0 = ti * 64;
    if (ti + 1 < nt) {
      STAGE(kv0 + 64, cur ^ 1);
      asm volatile("s_waitcnt vmcnt(4)" ::: "memory");  // cur's 4 loads done
    } else {
      asm volatile("s_waitcnt vmcnt(0)" ::: "memory");
    }
    __builtin_amdgcn_s_barrier();
    __builtin_amdgcn_sched_barrier(0);

    if (kv0 <= qb + 31) {            // not fully masked for this wave
      const u16* Kb = Ksh[cur];
      const u16* Vb = Vsh[cur];

      // ---- S^T = K Q^T : s[mi][ni][r] = S[q=mi*16+l15][k=ni*16+g*4+r] ----
      f32x4 s[2][4] = {};
      #pragma unroll
      for (int kc = 0; kc < 2; ++kc)
        #pragma unroll
        for (int ni = 0; ni < 4; ++ni) {
          int row = ni * 16 + l15;
          short8 kb = *(const short8*)&Kb[row * 64 + (((kc * 4 + g) ^ (row & 7)) << 3)];
          #pragma unroll
          for (int mi = 0; mi < 2; ++mi)
            s[mi][ni] = MFMA16(kb, qf[mi][kc], s[mi][ni]);
        }

      // ---- causal mask (diagonal tiles only): mask k > q ----
      if (kv0 + 63 > qb) {
        #pragma unroll
        for (int mi = 0; mi < 2; ++mi) {
          int qv = qb + mi * 16 + l15;
          #pragma unroll
          for (int ni = 0; ni < 4; ++ni)
            #pragma unroll
            for (int r = 0; r < 4; ++r)
              if (kv0 + ni * 16 + g * 4 + r > qv)
                s[mi][ni][r] = -1e30f;
        }
      }

      // ---- online softmax: in-lane reduce + 2 shfls (row is lane-local) ----
      float sc[2];
      #pragma unroll
      for (int mi = 0; mi < 2; ++mi) {
        float mx0 = fmaxf(fmaxf(s[mi][0][0], s[mi][0][1]),
                          fmaxf(s[mi][0][2], s[mi][0][3]));
        float mx1 = fmaxf(fmaxf(s[mi][1][0], s[mi][1][1]),
                          fmaxf(s[mi][1][2], s[mi][1][3]));
        float mx2 = fmaxf(fmaxf(s[mi][2][0], s[mi][2][1]),
                          fmaxf(s[mi][2][2], s[mi][2][3]));
        float mx3 = fmaxf(fmaxf(s[mi][3][0], s[mi][3][1]),
                          fmaxf(s[mi][3][2], s[mi][3][3]));
        float mx = fmaxf(fmaxf(mx0, mx1), fmaxf(mx2, mx3));
        mx = fmaxf(mx, __shfl_xor(mx, 16));
        mx = fmaxf(mx, __shfl_xor(mx, 32));
        float mn = fmaxf(mrun[mi], mx);
        sc[mi] = __expf(mrun[mi] - mn);
        mrun[mi] = mn;
        float rs = 0.f;
        #pragma unroll
        for (int ni = 0; ni < 4; ++ni)
          #pragma unroll
          for (int r = 0; r < 4; ++r) {
            float p = __expf(s[mi][ni][r] - mn);
            s[mi][ni][r] = p;
            rs += p;
          }
        rs += __shfl_xor(rs, 16);
        rs += __shfl_xor(rs, 32);
        lrun[mi] = lrun[mi] * sc[mi] + rs;
        #pragma unroll
        for (int nj = 0; nj < 4; ++nj) {
          oacc[mi][nj][0] *= sc[mi];
          oacc[mi][nj][1] *= sc[mi];
          oacc[mi][nj][2] *= sc[mi];
          oacc[mi][nj][3] *= sc[mi];
        }
      }

      // ---- P -> bf16 (cvt_pk pairs, 4 k-consecutive) -> per-wave LDS ----
      // Psh[w] is [16][64], reused for mi=0 then mi=1 (same-wave DS in-order;
      // may-alias addresses keep compiler from reordering write past read).
      u16* Pw = &Psh[w][0];
      short8 pb[2][2];
      #pragma unroll
      for (int mi = 0; mi < 2; ++mi) {
        #pragma unroll
        for (int ni = 0; ni < 4; ++ni) {
          int col = ni * 16 + g * 4;
          uint2 pv;
          pv.x = cvtpk(s[mi][ni][0], s[mi][ni][1]);
          pv.y = cvtpk(s[mi][ni][2], s[mi][ni][3]);
          *(uint2*)&Pw[l15 * 64 + (col ^ ((l15 & 7) << 3))] = pv;
        }
        #pragma unroll
        for (int kc = 0; kc < 2; ++kc)
          pb[mi][kc] = *(const short8*)&Pw[l15 * 64 + (((kc * 4 + g) ^ (l15 & 7)) << 3)];
      }

      // ---- O^T += V^T P : A = V^T frag (d rows), B = P frag (q rows) ----
      #pragma unroll
      for (int kc = 0; kc < 2; ++kc)
        #pragma unroll
        for (int nj = 0; nj < 4; ++nj) {
          int vrow = nj * 16 + l15;
          short8 vb = *(const short8*)&Vb[vrow * 64 + (((kc * 4 + g) ^ (vrow & 7)) << 3)];
          #pragma unroll
          for (int mi = 0; mi < 2; ++mi)
            oacc[mi][nj] = MFMA16(vb, pb[mi][kc], oacc[mi][nj]);
        }
    }

    __builtin_amdgcn_sched_barrier(0);
    __builtin_amdgcn_s_barrier();    // all reads of buf[cur] done -> reusable
    cur ^= 1;
  }
#undef STAGE

  // ---- epilogue: O over Q region, [bh][t][64], packed 8B stores ----
  #pragma unroll
  for (int mi = 0; mi < 2; ++mi) {
    float inv = 1.0f / lrun[mi];
    int t = qb + mi * 16 + l15;
    size_t base = (size_t)bh * 131072u + (size_t)t * 64u;
    #pragma unroll
    for (int nj = 0; nj < 4; ++nj) {
      uint2 o;
      o.x = cvtpk(oacc[mi][nj][0] * inv, oacc[mi][nj][1] * inv);
      o.y = cvtpk(oacc[mi][nj][2] * inv, oacc[mi][nj][3] * inv);
      *(uint2*)&O[base + nj * 16 + g * 4] = o;
    }
  }
}

// ---------------------------------------------------------------------------
extern "C" void kernel_launch(void* const* d_in, const int* in_sizes, int n_in,
                              void* d_out, int out_size, void* d_ws, size_t ws_size,
                              hipStream_t stream)
{
  (void)in_sizes; (void)n_in; (void)out_size; (void)ws_size;
  const float* x    = (const float*)d_in[0];   // [8192][1024] f32
  const float* wqkv = (const float*)d_in[1];   // [3072][1024] f32
  const float* wout = (const float*)d_in[2];   // [1024][1024] f32
  u16* ws  = (u16*)d_ws;
  u16* Qw   = ws;                  // Q [bh][t][64]; later attn O (same layout)
  u16* Kw   = ws + 8388608;        // K [bh][t][64]
  u16* VTw  = ws + 16777216;       // VT [bh][dh][2048]
  u16* wqb  = ws + 25165824;       // w_qkv bf16 [3072][1024]
  u16* wob  = ws + 28311552;       // w_out bf16 [1024][1024]
  u16* xb   = (u16*)d_out;         // x bf16 [8192][1024] staged in d_out
  float* y  = (float*)d_out;       // final f32 output (overwrites xb)

  hipLaunchKernelGGL(cvt_bf16, dim3(2048), dim3(256), 0, stream, x,    xb,  1048576);
  hipLaunchKernelGGL(cvt_bf16, dim3(1536), dim3(256), 0, stream, wqkv, wqb, 393216);
  hipLaunchKernelGGL(cvt_bf16, dim3(512),  dim3(256), 0, stream, wout, wob, 131072);
  hipLaunchKernelGGL((gemm_bt<1>), dim3(64, 24), dim3(256), 0, stream, xb, wqb, ws, (float*)nullptr);
  hipLaunchKernelGGL(attn,         dim3(1024),   dim3(256), 0, stream, Qw, Kw, VTw, Qw);
  hipLaunchKernelGGL((gemm_bt<2>), dim3(64, 8),  dim3(256), 0, stream, Qw, wob, (u16*)nullptr, y);
}

// Round 6
// 191.358 us; speedup vs baseline: 1.7296x; 1.0384x over previous
//
#include <hip/hip_runtime.h>

typedef __attribute__((ext_vector_type(8))) short short8;
typedef __attribute__((ext_vector_type(4))) float f32x4;
typedef __attribute__((ext_vector_type(4))) unsigned short us4;
typedef unsigned short u16;

#define MFMA16(a, b, c) __builtin_amdgcn_mfma_f32_16x16x32_bf16(a, b, c, 0, 0, 0)

static __device__ __forceinline__ u16 f2bf(float f) {
  union { float f; unsigned u; } v; v.f = f;
  unsigned r = v.u + 0x7fffu + ((v.u >> 16) & 1u);
  return (u16)(r >> 16);
}

static __device__ __forceinline__ unsigned cvtpk(float lo, float hi) {
  unsigned r;
  asm("v_cvt_pk_bf16_f32 %0, %1, %2" : "=v"(r) : "v"(lo), "v"(hi));
  return r;
}

static __device__ __forceinline__ void gl_lds16(const u16* g, u16* l) {
  __builtin_amdgcn_global_load_lds((const __attribute__((address_space(1))) void*)g,
                                   (__attribute__((address_space(3))) void*)l,
                                   16, 0, 0);
}

// ---------------------------------------------------------------------------
// f32 -> bf16 convert, 8 elems/thread, grid-stride.
// ---------------------------------------------------------------------------
__global__ __launch_bounds__(256)
void cvt_bf16(const float* __restrict__ src, u16* __restrict__ dst, int n8)
{
  int i = blockIdx.x * 256 + threadIdx.x;
  const int stride = gridDim.x * 256;
  for (; i < n8; i += stride) {
    f32x4 a = ((const f32x4*)src)[2 * i];
    f32x4 b = ((const f32x4*)src)[2 * i + 1];
    short8 o;
    o[0] = (short)f2bf(a[0]); o[1] = (short)f2bf(a[1]);
    o[2] = (short)f2bf(a[2]); o[3] = (short)f2bf(a[3]);
    o[4] = (short)f2bf(b[0]); o[5] = (short)f2bf(b[1]);
    o[6] = (short)f2bf(b[2]); o[7] = (short)f2bf(b[3]);
    ((short8*)dst)[i] = o;
  }
}

// ---------------------------------------------------------------------------
// GEMM: C(M x N) = A(M x 1024) * B^T(N x 1024), bf16 in, f32 acc.
// 1D grid with XCD-chunked 2D supertile decode: each XCD (bid%8) owns a
// contiguous (m-chunk x n-chunk) region sized to ~fit its private 4MB L2,
// eliminating the 24x re-stream of the A panel (was ~384MB FETCH for MODE=1).
// MODE=1: A natural [m][1024], 64x24 tiles; epilogue scatters Q (x0.125),
//         K ([bh][t][64]) and V transposed to VT[bh][dh][2048] into outp.
// MODE=2: A in headed layout [bh][t][64], 64x8 tiles; f32 store to outf.
// ---------------------------------------------------------------------------
template<int MODE>
__global__ __launch_bounds__(256)
void gemm_bt(const u16* __restrict__ A, const u16* __restrict__ B,
             u16* __restrict__ outp, float* __restrict__ outf)
{
  __shared__ u16 Ash[128 * 32];
  __shared__ u16 Bsh[128 * 32];
  const int tid = threadIdx.x;
  const int lane = tid & 63;
  const int l15 = lane & 15, g = lane >> 4;
  const int w = tid >> 6;
  const int wr = w >> 1, wc = w & 1;

  // XCD-chunked supertile decode (4 m-chunks x 2 n-chunks of tiles)
  const int bid = blockIdx.x;
  const int xcd = bid & 7, idx = bid >> 3;
  const int cx = xcd & 3, cy = xcd >> 2;
  int mt, nt;
  if (MODE == 1) {        // 64 x 24 tiles; 192 blocks/XCD = 16m x 12n
    mt = cx * 16 + (idx & 15);
    nt = cy * 12 + (idx >> 4);
  } else {                // 64 x 8 tiles; 64 blocks/XCD = 16m x 4n
    mt = cx * 16 + (idx & 15);
    nt = cy * 4 + (idx >> 4);
  }
  const long m0 = (long)mt * 128;
  const long n0 = (long)nt * 128;

  f32x4 acc[4][4] = {};

  // staging: 512 chunks of 16B per tile (A and B each), 2 chunks/thread
  const int c0 = tid, c1 = tid + 256;
  const long arow0 = m0 + (c0 >> 2), arow1 = m0 + (c1 >> 2);
  const u16* pa0;
  const u16* pa1;
  if (MODE == 2) {
    // headed A: element (m, k) at (b*16 + k/64)*131072 + t*64 + (k%64)
    int b0 = (int)(arow0 >> 11), t0 = (int)(arow0 & 2047);
    int b1 = (int)(arow1 >> 11), t1 = (int)(arow1 & 2047);
    pa0 = A + (size_t)(b0 * 16) * 131072u + (size_t)t0 * 64u + (c0 & 3) * 8;
    pa1 = A + (size_t)(b1 * 16) * 131072u + (size_t)t1 * 64u + (c1 & 3) * 8;
  } else {
    pa0 = A + arow0 * 1024 + (c0 & 3) * 8;
    pa1 = A + arow1 * 1024 + (c1 & 3) * 8;
  }
  const u16* pb0 = B + (n0 + (c0 >> 2)) * 1024 + (c0 & 3) * 8;
  const u16* pb1 = B + (n0 + (c1 >> 2)) * 1024 + (c1 & 3) * 8;
  u16* la0 = Ash + c0 * 8;
  u16* la1 = Ash + c1 * 8;
  u16* lb0 = Bsh + c0 * 8;
  u16* lb1 = Bsh + c1 * 8;

  // loop-invariant LDS fragment addresses
  const u16* afp[4];
  const u16* bfp[4];
  #pragma unroll
  for (int mi = 0; mi < 4; ++mi)
    afp[mi] = &Ash[(wr * 64 + mi * 16 + l15) * 32 + g * 8];
  #pragma unroll
  for (int ni = 0; ni < 4; ++ni)
    bfp[ni] = &Bsh[(wc * 64 + ni * 16 + l15) * 32 + g * 8];

  for (int k0 = 0; k0 < 1024; k0 += 32) {
    __syncthreads();
    gl_lds16(pa0, la0); gl_lds16(pa1, la1);
    gl_lds16(pb0, lb0); gl_lds16(pb1, lb1);
    if (MODE == 2) {
      long d = (k0 & 32) ? (131072 - 32) : 32;  // h-block crossing every 64
      pa0 += d; pa1 += d;
    } else {
      pa0 += 32; pa1 += 32;
    }
    pb0 += 32; pb1 += 32;
    __syncthreads();

    short8 af[4], bf[4];
    #pragma unroll
    for (int mi = 0; mi < 4; ++mi) af[mi] = *(const short8*)afp[mi];
    #pragma unroll
    for (int ni = 0; ni < 4; ++ni) bf[ni] = *(const short8*)bfp[ni];
    #pragma unroll
    for (int mi = 0; mi < 4; ++mi)
      #pragma unroll
      for (int ni = 0; ni < 4; ++ni)
        acc[mi][ni] = MFMA16(af[mi], bf[ni], acc[mi][ni]);
  }

  if (MODE == 2) {
    #pragma unroll
    for (int mi = 0; mi < 4; ++mi) {
      long m = m0 + wr * 64 + mi * 16 + g * 4;
      #pragma unroll
      for (int ni = 0; ni < 4; ++ni) {
        int n = (int)n0 + wc * 64 + ni * 16 + l15;
        #pragma unroll
        for (int r = 0; r < 4; ++r)
          outf[(m + r) * 1024 + n] = acc[mi][ni][r];
      }
    }
  } else {
    #pragma unroll
    for (int mi = 0; mi < 4; ++mi) {
      long m = m0 + wr * 64 + mi * 16 + g * 4;  // 4 consecutive rows m..m+3
      int b = (int)(m >> 11);
      int t = (int)(m & 2047);
      #pragma unroll
      for (int ni = 0; ni < 4; ++ni) {
        int e = (int)n0 + wc * 64 + ni * 16 + l15;   // 0..3071
        int sel = e >> 10;                            // 0=Q 1=K 2=V
        int ee = e & 1023;
        int h = ee >> 6, dh = ee & 63;
        size_t bh131k = (size_t)(b * 16 + h) * 131072u;
        if (sel < 2) {
          float sc = (sel == 0) ? 0.125f : 1.0f;     // fold 1/sqrt(64) into Q
          size_t base = (size_t)sel * 8388608u + bh131k + (size_t)t * 64u + dh;
          #pragma unroll
          for (int r = 0; r < 4; ++r)
            outp[base + (size_t)r * 64u] = f2bf(acc[mi][ni][r] * sc);
        } else {
          // V: write transposed, VT[bh][dh][t..t+3] (t % 4 == 0 -> 8B aligned)
          size_t base = 16777216u + bh131k + (size_t)dh * 2048u + (size_t)t;
          us4 v;
          #pragma unroll
          for (int r = 0; r < 4; ++r) v[r] = f2bf(acc[mi][ni][r]);
          *(us4*)&outp[base] = v;
        }
      }
    }
  }
}

// ---------------------------------------------------------------------------
// Causal flash attention, swapped-QK^T form. Q pre-scaled.
// Q/K: [bh][t][64], VT: [bh][dh][2048].
// 512 threads (8 waves), QBLK=256 q-rows/block (wave w owns 32 rows): K/V
// staging traffic, barriers and tile overhead halve per unit q-work vs 128.
// Heavy-first 1D grid (512 blocks); dbuf staging, counted vmcnt (T3/T4).
// Defer-max (T13): skip O/l rescale while the wave's row-max grows <= 8.
// LDS 48KB -> 3 blocks/CU = 24 waves/CU.
// O is written over the Q region ([bh][t][64]): each block reads only its own
// Q rows (into regs, at start) and writes only those rows (at end) -> safe.
// ---------------------------------------------------------------------------
__global__ __launch_bounds__(512, 4)
void attn(const u16* __restrict__ Q, const u16* __restrict__ K,
          const u16* __restrict__ VT, u16* __restrict__ O)
{
  __shared__ u16 Ksh[2][64 * 64];    // logical [kv][dh], swizzled, dbuf
  __shared__ u16 Vsh[2][64 * 64];    // logical [dh][kv], swizzled, dbuf
  __shared__ u16 Psh[8][16 * 64];    // per-wave [q%16][kv], swizzled, mi-reused

  const int tid = threadIdx.x;
  const int lane = tid & 63;
  const int l15 = lane & 15, g = lane >> 4;
  const int w = tid >> 6;            // 0..7
  const int bid = blockIdx.x;
  const int qi = 7 - (bid >> 6);     // heavy-first
  const int bh = bid & 63;
  const int q0 = qi * 256;
  const int qb = q0 + w * 32;
  const int nt = qi * 4 + 4;         // KV tiles for this block

  const u16* Qp = Q + (size_t)bh * 131072u;
  const u16* Kp = K + (size_t)bh * 131072u;
  const u16* Vp = VT + (size_t)bh * 131072u;

  // Q fragments in registers (B-frag: lane l15 = q row, g*8.. = d)
  short8 qf[2][2];
  #pragma unroll
  for (int mi = 0; mi < 2; ++mi)
    #pragma unroll
    for (int kc = 0; kc < 2; ++kc)
      qf[mi][kc] = *(const short8*)&Qp[(qb + mi * 16 + l15) * 64 + kc * 32 + g * 8];

  f32x4 oacc[2][4] = {};             // O^T: q = mi*16+l15, d = nj*16+g*4+r
  float mrun[2] = {-1e30f, -1e30f};
  float lrun[2] = {0.f, 0.f};

  // staging: 512 threads cover one 64x64 tile (512 chunks of 8 elems) each
  const int rA = tid >> 3, uA = ((tid & 7) ^ (rA & 7)) * 8;

  // source pre-swizzled so linear LDS dest == swizzled layout (rule #21)
#define STAGE(kv0s, b) do {                                            \
    gl_lds16(Kp + ((kv0s) + rA) * 64 + uA, Ksh[b] + tid * 8);          \
    gl_lds16(Vp + (size_t)rA * 2048u + (kv0s) + uA, Vsh[b] + tid * 8); \
  } while (0)

  STAGE(0, 0);
  int cur = 0;

  for (int ti = 0; ti < nt; ++ti) {
    const int kv0 = ti * 64;
    if (ti + 1 < nt) {
      STAGE(kv0 + 64, cur ^ 1);
      asm volatile("s_waitcnt vmcnt(2)" ::: "memory");  // cur's 2 loads done
    } else {
      asm volatile("s_waitcnt vmcnt(0)" ::: "memory");
    }
    __builtin_amdgcn_s_barrier();
    __builtin_amdgcn_sched_barrier(0);

    if (kv0 <= qb + 31) {            // not fully masked for this wave
      const u16* Kb = Ksh[cur];
      const u16* Vb = Vsh[cur];

      // ---- S^T = K Q^T : s[mi][ni][r] = S[q=mi*16+l15][k=ni*16+g*4+r] ----
      f32x4 s[2][4] = {};
      #pragma unroll
      for (int kc = 0; kc < 2; ++kc)
        #pragma unroll
        for (int ni = 0; ni < 4; ++ni) {
          int row = ni * 16 + l15;
          short8 kb = *(const short8*)&Kb[row * 64 + (((kc * 4 + g) ^ (row & 7)) << 3)];
          #pragma unroll
          for (int mi = 0; mi < 2; ++mi)
            s[mi][ni] = MFMA16(kb, qf[mi][kc], s[mi][ni]);
        }

      // ---- causal mask (diagonal tiles only): mask k > q ----
      if (kv0 + 63 > qb) {
        #pragma unroll
        for (int mi = 0; mi < 2; ++mi) {
          int qv = qb + mi * 16 + l15;
          #pragma unroll
          for (int ni = 0; ni < 4; ++ni)
            #pragma unroll
            for (int r = 0; r < 4; ++r)
              if (kv0 + ni * 16 + g * 4 + r > qv)
                s[mi][ni][r] = -1e30f;
        }
      }

      // ---- online softmax, in-lane reduce + 2 shfls; defer-max (T13) ----
      #pragma unroll
      for (int mi = 0; mi < 2; ++mi) {
        float mx0 = fmaxf(fmaxf(s[mi][0][0], s[mi][0][1]),
                          fmaxf(s[mi][0][2], s[mi][0][3]));
        float mx1 = fmaxf(fmaxf(s[mi][1][0], s[mi][1][1]),
                          fmaxf(s[mi][1][2], s[mi][1][3]));
        float mx2 = fmaxf(fmaxf(s[mi][2][0], s[mi][2][1]),
                          fmaxf(s[mi][2][2], s[mi][2][3]));
        float mx3 = fmaxf(fmaxf(s[mi][3][0], s[mi][3][1]),
                          fmaxf(s[mi][3][2], s[mi][3][3]));
        float mx = fmaxf(fmaxf(mx0, mx1), fmaxf(mx2, mx3));
        mx = fmaxf(mx, __shfl_xor(mx, 16));
        mx = fmaxf(mx, __shfl_xor(mx, 32));
        if (!__all(mx - mrun[mi] <= 8.0f)) {       // wave-uniform branch
          float mn = fmaxf(mrun[mi], mx);
          float sc = __expf(mrun[mi] - mn);
          mrun[mi] = mn;
          lrun[mi] *= sc;
          #pragma unroll
          for (int nj = 0; nj < 4; ++nj) {
            oacc[mi][nj][0] *= sc;
            oacc[mi][nj][1] *= sc;
            oacc[mi][nj][2] *= sc;
            oacc[mi][nj][3] *= sc;
          }
        }
        float mn = mrun[mi];
        float rs = 0.f;
        #pragma unroll
        for (int ni = 0; ni < 4; ++ni)
          #pragma unroll
          for (int r = 0; r < 4; ++r) {
            float p = __expf(s[mi][ni][r] - mn);
            s[mi][ni][r] = p;
            rs += p;
          }
        rs += __shfl_xor(rs, 16);
        rs += __shfl_xor(rs, 32);
        lrun[mi] += rs;
      }

      // ---- P -> bf16 (cvt_pk pairs, 4 k-consecutive) -> per-wave LDS ----
      // Psh[w] is [16][64], reused for mi=0 then mi=1 (same-wave DS in-order;
      // may-alias addresses keep compiler from reordering write past read).
      u16* Pw = &Psh[w][0];
      short8 pb[2][2];
      #pragma unroll
      for (int mi = 0; mi < 2; ++mi) {
        #pragma unroll
        for (int ni = 0; ni < 4; ++ni) {
          int col = ni * 16 + g * 4;
          uint2 pv;
          pv.x = cvtpk(s[mi][ni][0], s[mi][ni][1]);
          pv.y = cvtpk(s[mi][ni][2], s[mi][ni][3]);
          *(uint2*)&Pw[l15 * 64 + (col ^ ((l15 & 7) << 3))] = pv;
        }
        #pragma unroll
        for (int kc = 0; kc < 2; ++kc)
          pb[mi][kc] = *(const short8*)&Pw[l15 * 64 + (((kc * 4 + g) ^ (l15 & 7)) << 3)];
      }

      // ---- O^T += V^T P : A = V^T frag (d rows), B = P frag (q rows) ----
      #pragma unroll
      for (int kc = 0; kc < 2; ++kc)
        #pragma unroll
        for (int nj = 0; nj < 4; ++nj) {
          int vrow = nj * 16 + l15;
          short8 vb = *(const short8*)&Vb[vrow * 64 + (((kc * 4 + g) ^ (vrow & 7)) << 3)];
          #pragma unroll
          for (int mi = 0; mi < 2; ++mi)
            oacc[mi][nj] = MFMA16(vb, pb[mi][kc], oacc[mi][nj]);
        }
    }

    __builtin_amdgcn_sched_barrier(0);
    __builtin_amdgcn_s_barrier();    // all reads of buf[cur] done -> reusable
    cur ^= 1;
  }
#undef STAGE

  // ---- epilogue: O over Q region, [bh][t][64], packed 8B stores ----
  #pragma unroll
  for (int mi = 0; mi < 2; ++mi) {
    float inv = 1.0f / lrun[mi];
    int t = qb + mi * 16 + l15;
    size_t base = (size_t)bh * 131072u + (size_t)t * 64u;
    #pragma unroll
    for (int nj = 0; nj < 4; ++nj) {
      uint2 o;
      o.x = cvtpk(oacc[mi][nj][0] * inv, oacc[mi][nj][1] * inv);
      o.y = cvtpk(oacc[mi][nj][2] * inv, oacc[mi][nj][3] * inv);
      *(uint2*)&O[base + nj * 16 + g * 4] = o;
    }
  }
}

// ---------------------------------------------------------------------------
extern "C" void kernel_launch(void* const* d_in, const int* in_sizes, int n_in,
                              void* d_out, int out_size, void* d_ws, size_t ws_size,
                              hipStream_t stream)
{
  (void)in_sizes; (void)n_in; (void)out_size; (void)ws_size;
  const float* x    = (const float*)d_in[0];   // [8192][1024] f32
  const float* wqkv = (const float*)d_in[1];   // [3072][1024] f32
  const float* wout = (const float*)d_in[2];   // [1024][1024] f32
  u16* ws  = (u16*)d_ws;
  u16* Qw   = ws;                  // Q [bh][t][64]; later attn O (same layout)
  u16* Kw   = ws + 8388608;        // K [bh][t][64]
  u16* VTw  = ws + 16777216;       // VT [bh][dh][2048]
  u16* wqb  = ws + 25165824;       // w_qkv bf16 [3072][1024]
  u16* wob  = ws + 28311552;       // w_out bf16 [1024][1024]
  u16* xb   = (u16*)d_out;         // x bf16 [8192][1024] staged in d_out
  float* y  = (float*)d_out;       // final f32 output (overwrites xb)

  hipLaunchKernelGGL(cvt_bf16, dim3(2048), dim3(256), 0, stream, x,    xb,  1048576);
  hipLaunchKernelGGL(cvt_bf16, dim3(1536), dim3(256), 0, stream, wqkv, wqb, 393216);
  hipLaunchKernelGGL(cvt_bf16, dim3(512),  dim3(256), 0, stream, wout, wob, 131072);
  hipLaunchKernelGGL((gemm_bt<1>), dim3(1536), dim3(256), 0, stream, xb, wqb, ws, (float*)nullptr);
  hipLaunchKernelGGL(attn,         dim3(512),  dim3(512), 0, stream, Qw, Kw, VTw, Qw);
  hipLaunchKernelGGL((gemm_bt<2>), dim3(512),  dim3(256), 0, stream, Qw, wob, (u16*)nullptr, y);
}